// Round 1
// baseline (113.070 us; speedup 1.0000x reference)
//
#include <hip/hip_runtime.h>
#include <math.h>

#define HH 128
#define BB 2
#define FF 1024
#define CC 16
#define PIF 3.14159265358979323846f

// ---------------------------------------------------------------------------
// Pass 1: per-face precompute.
// For each (b,f): transform verts to pixel coords, build the three edge
// functions as affine forms in (py,px), fold in inv(area) so the hot loop
// evaluates barycentrics directly, fold (d+1)*0.5 into the depth affine,
// and store sign(area) plus a conservative tile-space bbox (8x8 tiles).
// Record layout (16 floats per face):
//   0..2  : LA0,LB0,LC0   (l0 = LA0*py + LB0*px + LC0)
//   3..5  : LA1,LB1,LC1
//   6..8  : LA2,LB2,LC2
//   9..11 : ZA,ZB,ZC      (zt_raw = ZA*py + ZB*px + ZC, already (d+1)/2)
//   12    : s = sign(area) (0 if degenerate)
//   13..15: pad
// Separate int array: packed tile bbox txmin|txmax<<8|tymin<<16|tymax<<24.
// ---------------------------------------------------------------------------
__global__ __launch_bounds__(256) void fof_pre(const float* __restrict__ v,
                                               float* __restrict__ fd,
                                               int* __restrict__ bb) {
    int idx = blockIdx.x * 256 + threadIdx.x;
    if (idx >= BB * FF) return;
    const float* vp = v + (size_t)idx * 9;

    float x0 = fmaf(vp[0], 64.f, 63.5f);
    float y0 = fmaf(vp[1], -64.f, 63.5f);
    float z0 = vp[2];
    float x1 = fmaf(vp[3], 64.f, 63.5f);
    float y1 = fmaf(vp[4], -64.f, 63.5f);
    float z1 = vp[5];
    float x2 = fmaf(vp[6], 64.f, 63.5f);
    float y2 = fmaf(vp[7], -64.f, 63.5f);
    float z2 = vp[8];

    // e0 = (x2-x1)*(py-y1) - (y2-y1)*(px-x1)
    float A0 = x2 - x1, B0 = -(y2 - y1), C0 = (y2 - y1) * x1 - (x2 - x1) * y1;
    // e1 = (x0-x2)*(py-y2) - (y0-y2)*(px-x2)
    float A1 = x0 - x2, B1 = -(y0 - y2), C1 = (y0 - y2) * x2 - (x0 - x2) * y2;
    // e2 = (x1-x0)*(py-y0) - (y1-y0)*(px-x0)
    float A2 = x1 - x0, B2 = -(y1 - y0), C2 = (y1 - y0) * x0 - (x1 - x0) * y0;

    float area = (x1 - x0) * (y2 - y0) - (x2 - x0) * (y1 - y0);
    float inv  = (area != 0.f) ? (1.f / area) : 0.f;
    float s    = (area > 0.f) ? 1.f : ((area < 0.f) ? -1.f : 0.f);

    float* o = fd + (size_t)idx * 16;
    o[0] = A0 * inv; o[1] = B0 * inv; o[2] = C0 * inv;
    o[3] = A1 * inv; o[4] = B1 * inv; o[5] = C1 * inv;
    o[6] = A2 * inv; o[7] = B2 * inv; o[8] = C2 * inv;
    // depth affine with (d+1)*0.5 folded in
    float hi = inv * 0.5f;
    o[9]  = (A0 * z0 + A1 * z1 + A2 * z2) * hi;
    o[10] = (B0 * z0 + B1 * z1 + B2 * z2) * hi;
    o[11] = (C0 * z0 + C1 * z1 + C2 * z2) * hi + 0.5f;
    o[12] = s;
    o[13] = 0.f; o[14] = 0.f; o[15] = 0.f;

    // conservative tile bbox (0.5px safety margin; tiles are 8x8)
    float xmn = fminf(x0, fminf(x1, x2)) - 0.5f;
    float xmx = fmaxf(x0, fmaxf(x1, x2)) + 0.5f;
    float ymn = fminf(y0, fminf(y1, y2)) - 0.5f;
    float ymx = fmaxf(y0, fmaxf(y1, y2)) + 0.5f;
    int txmin = (int)ceilf((xmn - 7.f) * 0.125f);
    int txmax = (int)floorf(xmx * 0.125f);
    int tymin = (int)ceilf((ymn - 7.f) * 0.125f);
    int tymax = (int)floorf(ymx * 0.125f);
    txmin = max(0, min(15, txmin)); txmax = max(0, min(15, txmax));
    tymin = max(0, min(15, tymin)); tymax = max(0, min(15, tymax));
    int pk;
    if (s == 0.f) {
        pk = 1 | (0 << 8) | (1 << 16) | (0 << 24);  // empty marker
    } else {
        pk = txmin | (txmax << 8) | (tymin << 16) | (tymax << 24);
    }
    bb[idx] = pk;
}

// ---------------------------------------------------------------------------
// Pass 2: main accumulation. One thread per pixel of an 8x8 tile; 4 waves per
// block, each wave owns a 256-face chunk; LDS reduction across waves at the
// end. Face records are read with wave-uniform indices -> scalar loads.
// ---------------------------------------------------------------------------
__global__ __launch_bounds__(256) void fof_main(const float* __restrict__ fd,
                                                const int* __restrict__ bb,
                                                float* __restrict__ out) {
    __shared__ float red[4][64][17];

    int blk  = blockIdx.x;        // 0..511
    int b    = blk >> 8;          // batch
    int tile = blk & 255;
    int ty   = tile >> 4;
    int tx   = tile & 15;
    int lane = threadIdx.x & 63;
    // readfirstlane: make the wave id provably wave-uniform so the face loop
    // index is uniform -> compiler emits s_load for face records.
    int wv = __builtin_amdgcn_readfirstlane(threadIdx.x >> 6);  // 0..3

    float px = (float)(tx * 8 + (lane & 7));
    float py = (float)(ty * 8 + (lane >> 3));

    float acc[CC];
#pragma unroll
    for (int k = 0; k < CC; ++k) acc[k] = 0.f;

    int base = b * FF;
    int fend = wv * 256 + 256;
    for (int f = wv * 256; f < fend; ++f) {
        int pk = bb[base + f];                       // uniform -> s_load
        int txmin = pk & 255;
        int txmax = (pk >> 8) & 255;
        int tymin = (pk >> 16) & 255;
        int tymax = (pk >> 24) & 255;
        if ((tx < txmin) | (tx > txmax) | (ty < tymin) | (ty > tymax))
            continue;                                // uniform scalar branch

        const float4* q = (const float4*)(fd + (size_t)(base + f) * 16);
        float4 q0 = q[0];   // LA0 LB0 LC0 LA1
        float4 q1 = q[1];   // LB1 LC1 LA2 LB2
        float4 q2 = q[2];   // LC2 ZA  ZB  ZC
        float4 q3 = q[3];   // s   --  --  --

        float l0 = fmaf(q0.x, py, fmaf(q0.y, px, q0.z));
        float l1 = fmaf(q0.w, py, fmaf(q1.x, px, q1.y));
        float l2 = fmaf(q1.z, py, fmaf(q1.w, px, q2.x));
        bool inside = (l0 >= 0.f) & (l1 >= 0.f) & (l2 >= 0.f);
        float w = inside ? q3.x : 0.f;

        if (__any(w != 0.f)) {
            float zt = fmaf(q2.y, py, fmaf(q2.z, px, q2.w));
            zt = fminf(fmaxf(zt, 0.f), 1.f);
            float t = PIF * zt;
            float s1, c1;
            __sincosf(t, &s1, &c1);
            acc[0] = fmaf(w, 1.f - zt, acc[0]);
            acc[1] = fmaf(w, s1, acc[1]);
            float twoc = c1 + c1;
            float skm2 = 0.f, skm1 = s1;   // sin(0*t), sin(1*t)
#pragma unroll
            for (int k = 2; k < CC; ++k) {
                float sk = fmaf(twoc, skm1, -skm2);
                acc[k] = fmaf(w, sk, acc[k]);
                skm2 = skm1;
                skm1 = sk;
            }
        }
    }

    // cross-wave reduction in LDS
#pragma unroll
    for (int k = 0; k < CC; ++k) red[wv][lane][k] = acc[k];
    __syncthreads();

    int px_i = threadIdx.x & 63;
    int kq   = threadIdx.x >> 6;   // 0..3 -> 4 coeffs each
    int xo   = tx * 8 + (px_i & 7);
    int yo   = ty * 8 + (px_i >> 3);
#pragma unroll
    for (int j = 0; j < 4; ++j) {
        int k = kq * 4 + j;
        float val = red[0][px_i][k] + red[1][px_i][k] +
                    red[2][px_i][k] + red[3][px_i][k];
        float scale = (k == 0) ? 1.f : (-2.f / (PIF * (float)k));
        out[(((b * CC + k) * HH) + yo) * HH + xo] = val * scale;
    }
}

extern "C" void kernel_launch(void* const* d_in, const int* in_sizes, int n_in,
                              void* d_out, int out_size, void* d_ws, size_t ws_size,
                              hipStream_t stream) {
    const float* v = (const float*)d_in[0];
    float* out = (float*)d_out;

    float* fd = (float*)d_ws;                       // 2048 * 16 floats = 128 KB
    int*   bb = (int*)((char*)d_ws + (size_t)BB * FF * 16 * sizeof(float)); // 8 KB

    fof_pre<<<(BB * FF + 255) / 256, 256, 0, stream>>>(v, fd, bb);
    fof_main<<<BB * 256, 256, 0, stream>>>(fd, bb, out);
}

// Round 3
// 109.208 us; speedup vs baseline: 1.0354x; 1.0354x over previous
//
#include <hip/hip_runtime.h>
#include <math.h>

#define HH 128
#define BB 2
#define FF 1024
#define CC 16
#define PIF 3.14159265358979323846f

// Fused single kernel. 512 blocks (B=2 x 256 8x8-pixel tiles) x 512 threads.
// Phase 1: stage the block's batch's raw verts (9 f32/face) + tile bbox in LDS.
// Phase 2: 8 waves x 128 faces. Ballot-cull 64 faces at a time against the
//          tile bbox, then iterate survivors. Edge functions / area / zt are
//          computed in f64 where they are EXACT (coords are multiples of 2^-18
//          bounded by 256 -> 26-bit values; products <= 52 bits; differences
//          exact), so the inside/winding decision matches exact arithmetic --
//          no compilation-dependent boundary-flip lottery.
// Phase 3: 8->4->2->1 LDS tree reduction (17-padded), wave 0 stores with the
//          -2/(k pi) scale folded in.

union ShU {
    struct {
        float4 rec[FF * 3];   // raw verts, 9 floats + 3 pad per face (48 B)
        int    bbox[FF];      // packed tile bbox
    } a;                      // 53248 B
    struct {
        float A[4][64][17];   // 17408 B
        float B[2][64][17];   // 8704 B
    } r;
};

__global__ __launch_bounds__(512, 4) void fof_fused(const float* __restrict__ v,
                                                    float* __restrict__ out) {
#pragma clang fp contract(off)
    __shared__ ShU sh;

    int blk  = blockIdx.x;          // 0..511
    int b    = blk >> 8;
    int tile = blk & 255;
    int ty   = tile >> 4;
    int tx   = tile & 15;

    // ---------------- phase 1: verts + bbox into LDS ----------------
    for (int f = threadIdx.x; f < FF; f += 512) {
        const float* vp = v + ((size_t)b * FF + f) * 9;
        float w0 = vp[0], w1 = vp[1], w2 = vp[2];
        float w3 = vp[3], w4 = vp[4], w5 = vp[5];
        float w6 = vp[6], w7 = vp[7], w8 = vp[8];
        sh.a.rec[f * 3 + 0] = make_float4(w0, w1, w2, w3);
        sh.a.rec[f * 3 + 1] = make_float4(w4, w5, w6, w7);
        sh.a.rec[f * 3 + 2] = make_float4(w8, 0.f, 0.f, 0.f);

        // conservative f32 bbox (0.5px margin >> f32 coord error ~1e-4)
        float x0 = fmaf(w0, 64.f, 63.5f), y0 = fmaf(w1, -64.f, 63.5f);
        float x1 = fmaf(w3, 64.f, 63.5f), y1 = fmaf(w4, -64.f, 63.5f);
        float x2 = fmaf(w6, 64.f, 63.5f), y2 = fmaf(w7, -64.f, 63.5f);
        float xmn = fminf(x0, fminf(x1, x2)) - 0.5f;
        float xmx = fmaxf(x0, fmaxf(x1, x2)) + 0.5f;
        float ymn = fminf(y0, fminf(y1, y2)) - 0.5f;
        float ymx = fmaxf(y0, fmaxf(y1, y2)) + 0.5f;
        int txmin = (int)ceilf((xmn - 7.f) * 0.125f);
        int txmax = (int)floorf(xmx * 0.125f);
        int tymin = (int)ceilf((ymn - 7.f) * 0.125f);
        int tymax = (int)floorf(ymx * 0.125f);
        txmin = max(0, min(15, txmin)); txmax = max(0, min(15, txmax));
        tymin = max(0, min(15, tymin)); tymax = max(0, min(15, tymax));
        sh.a.bbox[f] = txmin | (txmax << 8) | (tymin << 16) | (tymax << 24);
    }
    __syncthreads();

    // ---------------- phase 2: ballot-culled exact accumulation ----------------
    int wv   = __builtin_amdgcn_readfirstlane((int)(threadIdx.x >> 6));  // 0..7
    int lane = threadIdx.x & 63;

    double pxd = (double)(tx * 8 + (lane & 7));
    double pyd = (double)(ty * 8 + (lane >> 3));

    float acc[CC];
#pragma unroll
    for (int k = 0; k < CC; ++k) acc[k] = 0.f;

    for (int c = 0; c < 2; ++c) {
        int fb = wv * 128 + c * 64;
        int pk = sh.a.bbox[fb + lane];
        int txmin = pk & 255, txmax = (pk >> 8) & 255;
        int tymin = (pk >> 16) & 255, tymax = (pk >> 24) & 255;
        bool pass = !((tx < txmin) | (tx > txmax) | (ty < tymin) | (ty > tymax));
        unsigned long long m = __ballot(pass);

        while (m) {
            int j = __builtin_ctzll(m);
            m &= m - 1;
            int f = fb + j;                         // wave-uniform

            float4 a0 = sh.a.rec[f * 3 + 0];        // uniform -> broadcast
            float4 a1 = sh.a.rec[f * 3 + 1];
            float4 a2 = sh.a.rec[f * 3 + 2];

            // exact f64 pixel-space verts (v*64 exact; +63.5 exact for |v|>2^-30)
            double X0 = fma((double)a0.x,  64.0, 63.5);
            double Y0 = fma((double)a0.y, -64.0, 63.5);
            double Z0 = (double)a0.z;
            double X1 = fma((double)a0.w,  64.0, 63.5);
            double Y1 = fma((double)a1.x, -64.0, 63.5);
            double Z1 = (double)a1.y;
            double X2 = fma((double)a1.z,  64.0, 63.5);
            double Y2 = fma((double)a1.w, -64.0, 63.5);
            double Z2 = (double)a2.x;

            double d0x = X2 - X1, d0y = Y2 - Y1;
            double d1x = X0 - X2, d1y = Y0 - Y2;
            double d2x = X1 - X0, d2y = Y1 - Y0;
            double area = d1x * d2y - d1y * d2x;    // exact
            if (area == 0.0) continue;              // w=0 for all pixels

            double sg = (area > 0.0) ? 1.0 : -1.0;
            double e0 = d0x * (pyd - Y1) - d0y * (pxd - X1);  // exact
            double e1 = d1x * (pyd - Y2) - d1y * (pxd - X2);  // exact
            double e2 = d2x * (pyd - Y0) - d2y * (pxd - X0);  // exact
            bool inside = (e0 * sg >= 0.0) & (e1 * sg >= 0.0) & (e2 * sg >= 0.0);

            if (__any(inside)) {
                double invA = 1.0 / area;
                double l0 = e0 * invA, l1 = e1 * invA, l2 = e2 * invA;
                double u = (((l0 * Z0 + l1 * Z1) + l2 * Z2) + 1.0) * 0.5;
                u = fmin(fmax(u, 0.0), 1.0);
                float zt = (float)u;
                float w = inside ? (float)sg : 0.f;

                float t = PIF * zt;
                float s1, c1;
                __sincosf(t, &s1, &c1);
                acc[0] = fmaf(w, 1.f - zt, acc[0]);
                acc[1] = fmaf(w, s1, acc[1]);
                float twoc = c1 + c1;
                float skm2 = 0.f, skm1 = s1;
#pragma unroll
                for (int k = 2; k < CC; ++k) {
                    float sk = fmaf(twoc, skm1, -skm2);
                    acc[k] = fmaf(w, sk, acc[k]);
                    skm2 = skm1;
                    skm1 = sk;
                }
            }
        }
    }

    // ---------------- phase 3: 8->4->2->1 tree reduction ----------------
    __syncthreads();                    // records dead; stage region live
    if (wv >= 4) {
#pragma unroll
        for (int k = 0; k < CC; ++k) sh.r.A[wv - 4][lane][k] = acc[k];
    }
    __syncthreads();
    if (wv < 4) {
#pragma unroll
        for (int k = 0; k < CC; ++k) acc[k] += sh.r.A[wv][lane][k];
    }
    if (wv == 2 || wv == 3) {
#pragma unroll
        for (int k = 0; k < CC; ++k) sh.r.B[wv - 2][lane][k] = acc[k];
    }
    __syncthreads();
    if (wv < 2) {
#pragma unroll
        for (int k = 0; k < CC; ++k) acc[k] += sh.r.B[wv][lane][k];
    }
    if (wv == 1) {                      // A reads all happened before prev sync
#pragma unroll
        for (int k = 0; k < CC; ++k) sh.r.A[0][lane][k] = acc[k];
    }
    __syncthreads();
    if (wv == 0) {
        int xo = tx * 8 + (lane & 7);
        int yo = ty * 8 + (lane >> 3);
#pragma unroll
        for (int k = 0; k < CC; ++k) {
            float val = acc[k] + sh.r.A[0][lane][k];
            float scale = (k == 0) ? 1.f : (-2.f / (PIF * (float)k));
            out[(((b * CC + k) * HH) + yo) * HH + xo] = val * scale;
        }
    }
}

extern "C" void kernel_launch(void* const* d_in, const int* in_sizes, int n_in,
                              void* d_out, int out_size, void* d_ws, size_t ws_size,
                              hipStream_t stream) {
    const float* v = (const float*)d_in[0];
    float* out = (float*)d_out;
    fof_fused<<<BB * 256, 512, 0, stream>>>(v, out);
}

// Round 4
// 85.610 us; speedup vs baseline: 1.3208x; 1.2756x over previous
//
#include <hip/hip_runtime.h>
#include <math.h>

#define HH 128
#define BB 2
#define FF 1024
#define CC 16
#define PIF 3.14159265358979323846f
#define RS 14   // doubles per face record

// ---------------------------------------------------------------------------
// Kernel 1: per-face f64 affine coefficients (computed ONCE, not per tile).
//   l_i(px,py) = A_i*py + B_i*px + C_i   (1/area folded in)
//   zt(px,py)  = clamp(ZA*py + ZB*px + ZC, 0, 1)   (+1, *0.5 folded in)
// f64 keeps the inside/winding decisions at ~1e-15 relative error vs the
// np-f64 reference -- boundary-flip probability is negligible (R3 evidence:
// f64 decisions -> absmax 0.0078 vs threshold 0.565).
// Record: [A0 B0 C0 A1 B1 C1 A2 B2 C2 sg ZA ZB ZC pad]  (112 B)
// ---------------------------------------------------------------------------
__global__ __launch_bounds__(256) void fof_setup(const float* __restrict__ v,
                                                 double* __restrict__ rec,
                                                 int* __restrict__ bbox) {
#pragma clang fp contract(off)
    int idx = blockIdx.x * 256 + threadIdx.x;
    if (idx >= BB * FF) return;
    const float* vp = v + (size_t)idx * 9;

    double X0 = fma((double)vp[0],  64.0, 63.5);
    double Y0 = fma((double)vp[1], -64.0, 63.5);
    double Z0 = (double)vp[2];
    double X1 = fma((double)vp[3],  64.0, 63.5);
    double Y1 = fma((double)vp[4], -64.0, 63.5);
    double Z1 = (double)vp[5];
    double X2 = fma((double)vp[6],  64.0, 63.5);
    double Y2 = fma((double)vp[7], -64.0, 63.5);
    double Z2 = (double)vp[8];

    double d0x = X2 - X1, d0y = Y2 - Y1;
    double d1x = X0 - X2, d1y = Y0 - Y2;
    double d2x = X1 - X0, d2y = Y1 - Y0;
    double area = d1x * d2y - d1y * d2x;
    double inv  = (area != 0.0) ? 1.0 / area : 0.0;
    double sg   = (area > 0.0) ? 1.0 : ((area < 0.0) ? -1.0 : 0.0);

    // e0 = d0x*(py-Y1) - d0y*(px-X1) = d0x*py - d0y*px + (d0y*X1 - d0x*Y1)
    double A0 = d0x * inv, B0 = -d0y * inv, C0 = (d0y * X1 - d0x * Y1) * inv;
    double A1 = d1x * inv, B1 = -d1y * inv, C1 = (d1y * X2 - d1x * Y2) * inv;
    double A2 = d2x * inv, B2 = -d2y * inv, C2 = (d2y * X0 - d2x * Y0) * inv;

    double ZA = (A0 * Z0 + A1 * Z1 + A2 * Z2) * 0.5;
    double ZB = (B0 * Z0 + B1 * Z1 + B2 * Z2) * 0.5;
    double ZC = (C0 * Z0 + C1 * Z1 + C2 * Z2 + 1.0) * 0.5;

    double* r = rec + (size_t)idx * RS;
    r[0] = A0; r[1] = B0; r[2] = C0;
    r[3] = A1; r[4] = B1; r[5] = C1;
    r[6] = A2; r[7] = B2; r[8] = C2;
    r[9] = sg; r[10] = ZA; r[11] = ZB; r[12] = ZC; r[13] = 0.0;

    // conservative tile bbox (8x8 tiles, 0.5px margin)
    float x0 = (float)X0, y0 = (float)Y0;
    float x1 = (float)X1, y1 = (float)Y1;
    float x2 = (float)X2, y2 = (float)Y2;
    float xmn = fminf(x0, fminf(x1, x2)) - 0.5f;
    float xmx = fmaxf(x0, fmaxf(x1, x2)) + 0.5f;
    float ymn = fminf(y0, fminf(y1, y2)) - 0.5f;
    float ymx = fmaxf(y0, fmaxf(y1, y2)) + 0.5f;
    int txmin = (int)ceilf((xmn - 7.f) * 0.125f);
    int txmax = (int)floorf(xmx * 0.125f);
    int tymin = (int)ceilf((ymn - 7.f) * 0.125f);
    int tymax = (int)floorf(ymx * 0.125f);
    txmin = max(0, min(15, txmin)); txmax = max(0, min(15, txmax));
    tymin = max(0, min(15, tymin)); tymax = max(0, min(15, tymax));
    bbox[idx] = (sg == 0.0) ? (1 | (0 << 8) | (1 << 16) | (0 << 24))
                            : (txmin | (txmax << 8) | (tymin << 16) | (tymax << 24));
}

// ---------------------------------------------------------------------------
// Kernel 2: main accumulation. 1024 blocks = (b, half, tile) x 512 threads.
// 8 waves x 64 faces each (of this half's 512). Ballot-cull against tile
// bbox, iterate survivors; records via wave-uniform scalar loads (L2-hot).
// 8->4->2->1 LDS tree, wv0 writes this half's partial to ws.
// ---------------------------------------------------------------------------
__global__ __launch_bounds__(512) void fof_main(const double* __restrict__ rec,
                                                const int* __restrict__ bbox,
                                                float* __restrict__ part) {
    __shared__ float S1[4][64][17];
    __shared__ float S2[2][64][17];
    __shared__ float S3[64][17];

    int blk  = blockIdx.x;            // 0..1023
    int b    = blk >> 9;
    int rest = blk & 511;
    int half = rest >> 8;
    int tile = rest & 255;
    int ty   = tile >> 4;
    int tx   = tile & 15;
    int wv   = __builtin_amdgcn_readfirstlane((int)(threadIdx.x >> 6));  // 0..7
    int lane = threadIdx.x & 63;

    double pxd = (double)(tx * 8 + (lane & 7));
    double pyd = (double)(ty * 8 + (lane >> 3));

    float acc[CC];
#pragma unroll
    for (int k = 0; k < CC; ++k) acc[k] = 0.f;

    int gfb = b * FF + half * 512 + wv * 64;   // this wave's 64-face chunk

    // lane-parallel bbox test -> 64-bit survivor mask
    int pk = bbox[gfb + lane];
    int txmin = pk & 255, txmax = (pk >> 8) & 255;
    int tymin = (pk >> 16) & 255, tymax = (pk >> 24) & 255;
    bool pass = !((tx < txmin) | (tx > txmax) | (ty < tymin) | (ty > tymax));
    unsigned long long m = __ballot(pass);

    const double* rp = rec + (size_t)gfb * RS;
    while (m) {
        int j = __builtin_ctzll(m);
        m &= m - 1;
        j = __builtin_amdgcn_readfirstlane(j);        // force SGPR index
        const double* r = rp + j * RS;                // -> s_load

        double l0 = fma(r[0], pyd, fma(r[1], pxd, r[2]));
        double l1 = fma(r[3], pyd, fma(r[4], pxd, r[5]));
        double l2 = fma(r[6], pyd, fma(r[7], pxd, r[8]));
        bool inside = (l0 >= 0.0) & (l1 >= 0.0) & (l2 >= 0.0);

        if (__any(inside)) {
            double u = fma(r[10], pyd, fma(r[11], pxd, r[12]));
            u = fmin(fmax(u, 0.0), 1.0);
            float zt = (float)u;
            float w  = inside ? (float)r[9] : 0.f;

            float t = PIF * zt;
            float s1, c1;
            __sincosf(t, &s1, &c1);
            acc[0] = fmaf(w, 1.f - zt, acc[0]);
            acc[1] = fmaf(w, s1, acc[1]);
            float twoc = c1 + c1;
            float skm2 = 0.f, skm1 = s1;
#pragma unroll
            for (int k = 2; k < CC; ++k) {
                float sk = fmaf(twoc, skm1, -skm2);
                acc[k] = fmaf(w, sk, acc[k]);
                skm2 = skm1;
                skm1 = sk;
            }
        }
    }

    // 8 -> 4 -> 2 -> 1 tree reduction (disjoint stage buffers, no WAR races)
    if (wv >= 4) {
#pragma unroll
        for (int k = 0; k < CC; ++k) S1[wv - 4][lane][k] = acc[k];
    }
    __syncthreads();
    if (wv < 4) {
#pragma unroll
        for (int k = 0; k < CC; ++k) acc[k] += S1[wv][lane][k];
    }
    if (wv == 2 || wv == 3) {
#pragma unroll
        for (int k = 0; k < CC; ++k) S2[wv - 2][lane][k] = acc[k];
    }
    __syncthreads();
    if (wv < 2) {
#pragma unroll
        for (int k = 0; k < CC; ++k) acc[k] += S2[wv][lane][k];
    }
    if (wv == 1) {
#pragma unroll
        for (int k = 0; k < CC; ++k) S3[lane][k] = acc[k];
    }
    __syncthreads();
    if (wv == 0) {
        int xo = tx * 8 + (lane & 7);
        int yo = ty * 8 + (lane >> 3);
#pragma unroll
        for (int k = 0; k < CC; ++k) {
            part[(((b * 2 + half) * CC + k) * (HH * HH)) + yo * HH + xo] =
                acc[k] + S3[lane][k];
        }
    }
}

// ---------------------------------------------------------------------------
// Kernel 3: combine the two half partials, apply -2/(k*pi) scale. float4.
// ---------------------------------------------------------------------------
__global__ __launch_bounds__(256) void fof_combine(const float4* __restrict__ part4,
                                                   float4* __restrict__ out4) {
    int i   = blockIdx.x * 256 + threadIdx.x;   // 0..131071
    int b   = i >> 16;
    int rem = i & 65535;
    int k   = rem >> 12;
    int r   = rem & 4095;
    float4 p0 = part4[(b * 32 + k) * 4096 + r];
    float4 p1 = part4[(b * 32 + 16 + k) * 4096 + r];
    float scale = (k == 0) ? 1.f : (-2.f / (PIF * (float)k));
    float4 o;
    o.x = (p0.x + p1.x) * scale;
    o.y = (p0.y + p1.y) * scale;
    o.z = (p0.z + p1.z) * scale;
    o.w = (p0.w + p1.w) * scale;
    out4[(b * 16 + k) * 4096 + r] = o;
}

extern "C" void kernel_launch(void* const* d_in, const int* in_sizes, int n_in,
                              void* d_out, int out_size, void* d_ws, size_t ws_size,
                              hipStream_t stream) {
    const float* v = (const float*)d_in[0];
    float* out = (float*)d_out;

    // ws layout: rec 2048*14*8 = 229376 B | bbox 2048*4 = 8192 B | partials 4 MB
    double* rec  = (double*)d_ws;
    int*    bbox = (int*)((char*)d_ws + 229376);
    float*  part = (float*)((char*)d_ws + 237568);

    fof_setup<<<(BB * FF + 255) / 256, 256, 0, stream>>>(v, rec, bbox);
    fof_main<<<BB * 2 * 256, 512, 0, stream>>>(rec, bbox, part);
    fof_combine<<<512, 256, 0, stream>>>((const float4*)part, (float4*)out);
}

// Round 6
// 81.239 us; speedup vs baseline: 1.3918x; 1.0538x over previous
//
#include <hip/hip_runtime.h>
#include <math.h>

#define HH 128
#define BB 2
#define FF 1024
#define CC 16
#define PIF 3.14159265358979323846f

typedef float f2 __attribute__((ext_vector_type(2)));

// ---------------------------------------------------------------------------
// Kernel 1: per-face setup (once, 2048 threads total).
// f32 record (16 floats, 64B -> one s_load_dwordx16):
//   [0..8]  A0 B0 C0 A1 B1 C1 A2 B2 C2   (l_i = A*py + B*px + C, 1/area folded)
//   [9..11] ZA ZB ZC                     (zt = clamp(ZA*py+ZB*px+ZC, 0, 1))
//   [12]    sg   [13] eps (f32 sign-uncertainty band)   [14..15] pad
// f64 record (10 doubles): [0..8] the same A..C in f64, [9] pad. Used only
// when some lane's |l_f32| < eps: the f64 signs reproduce R3/R4's exact
// decisions (absmax 0.0078 evidence), so no boundary-flip lottery.
// ---------------------------------------------------------------------------
__global__ __launch_bounds__(256) void fof_setup(const float* __restrict__ v,
                                                 float* __restrict__ recf,
                                                 double* __restrict__ recd,
                                                 int* __restrict__ bbox) {
    int idx = blockIdx.x * 256 + threadIdx.x;
    if (idx >= BB * FF) return;
    const float* vp = v + (size_t)idx * 9;

    double X0 = fma((double)vp[0],  64.0, 63.5);
    double Y0 = fma((double)vp[1], -64.0, 63.5);
    double Z0 = (double)vp[2];
    double X1 = fma((double)vp[3],  64.0, 63.5);
    double Y1 = fma((double)vp[4], -64.0, 63.5);
    double Z1 = (double)vp[5];
    double X2 = fma((double)vp[6],  64.0, 63.5);
    double Y2 = fma((double)vp[7], -64.0, 63.5);
    double Z2 = (double)vp[8];

    double d0x = X2 - X1, d0y = Y2 - Y1;
    double d1x = X0 - X2, d1y = Y0 - Y2;
    double d2x = X1 - X0, d2y = Y1 - Y0;
    double area = d1x * d2y - d1y * d2x;
    double inv  = (area != 0.0) ? 1.0 / area : 0.0;
    double sg   = (area > 0.0) ? 1.0 : ((area < 0.0) ? -1.0 : 0.0);

    double A0 = d0x * inv, B0 = -d0y * inv, C0 = (d0y * X1 - d0x * Y1) * inv;
    double A1 = d1x * inv, B1 = -d1y * inv, C1 = (d1y * X2 - d1x * Y2) * inv;
    double A2 = d2x * inv, B2 = -d2y * inv, C2 = (d2y * X0 - d2x * Y0) * inv;

    double ZA = (A0 * Z0 + A1 * Z1 + A2 * Z2) * 0.5;
    double ZB = (B0 * Z0 + B1 * Z1 + B2 * Z2) * 0.5;
    double ZC = (C0 * Z0 + C1 * Z1 + C2 * Z2 + 1.0) * 0.5;

    // f32 sign-uncertainty band: covers f64->f32 coeff conversion (2^-24 rel)
    // + 2-fma f32 eval rounding, on |py|,|px| <= 127 (135 margin). 3x slack.
    double M0 = (fabs(A0) + fabs(B0)) * 135.0 + fabs(C0);
    double M1 = (fabs(A1) + fabs(B1)) * 135.0 + fabs(C1);
    double M2 = (fabs(A2) + fabs(B2)) * 135.0 + fabs(C2);
    float eps = (float)(1e-6 * fmax(M0, fmax(M1, M2)));

    float* rf = recf + (size_t)idx * 16;
    rf[0] = (float)A0; rf[1] = (float)B0; rf[2] = (float)C0;
    rf[3] = (float)A1; rf[4] = (float)B1; rf[5] = (float)C1;
    rf[6] = (float)A2; rf[7] = (float)B2; rf[8] = (float)C2;
    rf[9] = (float)ZA; rf[10] = (float)ZB; rf[11] = (float)ZC;
    rf[12] = (float)sg; rf[13] = eps; rf[14] = 0.f; rf[15] = 0.f;

    double* rd = recd + (size_t)idx * 10;
    rd[0] = A0; rd[1] = B0; rd[2] = C0;
    rd[3] = A1; rd[4] = B1; rd[5] = C1;
    rd[6] = A2; rd[7] = B2; rd[8] = C2; rd[9] = 0.0;

    float x0 = (float)X0, y0 = (float)Y0;
    float x1 = (float)X1, y1 = (float)Y1;
    float x2 = (float)X2, y2 = (float)Y2;
    float xmn = fminf(x0, fminf(x1, x2)) - 0.5f;
    float xmx = fmaxf(x0, fmaxf(x1, x2)) + 0.5f;
    float ymn = fminf(y0, fminf(y1, y2)) - 0.5f;
    float ymx = fmaxf(y0, fmaxf(y1, y2)) + 0.5f;
    int txmin = (int)ceilf((xmn - 7.f) * 0.125f);
    int txmax = (int)floorf(xmx * 0.125f);
    int tymin = (int)ceilf((ymn - 7.f) * 0.125f);
    int tymax = (int)floorf(ymx * 0.125f);
    txmin = max(0, min(15, txmin)); txmax = max(0, min(15, txmax));
    tymin = max(0, min(15, tymin)); tymax = max(0, min(15, tymax));
    bbox[idx] = (sg == 0.0) ? (1 | (0 << 8) | (1 << 16) | (0 << 24))
                            : (txmin | (txmax << 8) | (tymin << 16) | (tymax << 24));
}

// ---------------------------------------------------------------------------
// Kernel 2: main. 512 blocks = (b, tile) x 1024 threads; 16 waves x 64 faces
// covers all 1024 faces -> block writes FINAL scaled output (no combine pass).
// Per survivor: one s_load_dwordx16 + 8 f32 FMA (l,zt) + 3 HW trans +
// 13 v_pk_fma_f32 (double-step Chebyshev on (odd,even) pairs) + rare f64
// fallback for edge-band lanes. Reduction: 16->8->4->2->1 LDS tree.
// ---------------------------------------------------------------------------
__global__ __launch_bounds__(1024) void fof_main(const float* __restrict__ recf,
                                                 const double* __restrict__ recd,
                                                 const int* __restrict__ bbox,
                                                 float* __restrict__ out) {
    __shared__ float S1[8][64][17];
    __shared__ float S2[4][64][17];
    __shared__ float S3[2][64][17];
    __shared__ float S4[64][17];

    int blk  = blockIdx.x;          // 0..511
    int b    = blk >> 8;
    int tile = blk & 255;
    int ty   = tile >> 4;
    int tx   = tile & 15;
    int wv   = __builtin_amdgcn_readfirstlane((int)(threadIdx.x >> 6));  // 0..15
    int lane = threadIdx.x & 63;

    float px = (float)(tx * 8 + (lane & 7));
    float py = (float)(ty * 8 + (lane >> 3));

    float acc0 = 0.f, acc15 = 0.f;
    f2 accP[7];
#pragma unroll
    for (int j = 0; j < 7; ++j) { accP[j].x = 0.f; accP[j].y = 0.f; }

    int gfb = b * FF + wv * 64;     // this wave's 64-face chunk

    int pk = bbox[gfb + lane];
    int txmin = pk & 255, txmax = (pk >> 8) & 255;
    int tymin = (pk >> 16) & 255, tymax = (pk >> 24) & 255;
    bool pass = !((tx < txmin) | (tx > txmax) | (ty < tymin) | (ty > tymax));
    unsigned long long m = __ballot(pass);

    while (m) {
        int j = __builtin_ctzll(m);
        m &= m - 1;
        j = __builtin_amdgcn_readfirstlane(j);           // wave-uniform index
        const float* r = recf + (size_t)(gfb + j) * 16;  // -> s_load_dwordx16

        float l0 = fmaf(r[0], py, fmaf(r[1], px, r[2]));
        float l1 = fmaf(r[3], py, fmaf(r[4], px, r[5]));
        float l2 = fmaf(r[6], py, fmaf(r[7], px, r[8]));
        float eps = r[13];
        bool inside = (l0 >= 0.f) & (l1 >= 0.f) & (l2 >= 0.f);
        bool unc = (__builtin_fabsf(l0) < eps) | (__builtin_fabsf(l1) < eps) |
                   (__builtin_fabsf(l2) < eps);
        if (__builtin_expect(__any(unc), 0)) {           // rare exact path
            const double* rd = recd + (size_t)(gfb + j) * 10;
            double pyd = (double)py, pxd = (double)px;
            double L0 = fma(rd[0], pyd, fma(rd[1], pxd, rd[2]));
            double L1 = fma(rd[3], pyd, fma(rd[4], pxd, rd[5]));
            double L2 = fma(rd[6], pyd, fma(rd[7], pxd, rd[8]));
            inside = (L0 >= 0.0) & (L1 >= 0.0) & (L2 >= 0.0);
        }
        float w = inside ? r[12] : 0.f;

        if (__any(w != 0.f)) {
            float zt = fmaf(r[9], py, fmaf(r[10], px, r[11]));
            zt = fminf(fmaxf(zt, 0.f), 1.f);
            // HW trig in revolutions: sin(pi*zt)=vsin(zt/2), sin(2pi*zt)=vsin(zt),
            // cos(2pi*zt)=vcos(zt). Range [0,1] rev -> no argument reduction.
            float hz = 0.5f * zt;
            float s1, s2, c2;
            asm("v_sin_f32 %0, %1" : "=v"(s1) : "v"(hz));
            asm("v_sin_f32 %0, %1" : "=v"(s2) : "v"(zt));
            asm("v_cos_f32 %0, %1" : "=v"(c2) : "v"(zt));
            float twoc2 = c2 + c2;

            acc0 = fmaf(w, 1.f - zt, acc0);
            f2 w2;  w2.x = w;      w2.y = w;
            f2 t2;  t2.x = twoc2;  t2.y = twoc2;
            f2 um1; um1.x = -s1;   um1.y = 0.f;   // (s_{-1}, s_0)
            f2 u0;  u0.x = s1;     u0.y = s2;     // (s_1, s_2)
            accP[0] += w2 * u0;
            f2 u1 = t2 * u0 - um1;  accP[1] += w2 * u1;   // (s_3, s_4)
            f2 u2 = t2 * u1 - u0;   accP[2] += w2 * u2;   // (s_5, s_6)
            f2 u3 = t2 * u2 - u1;   accP[3] += w2 * u3;   // (s_7, s_8)
            f2 u4 = t2 * u3 - u2;   accP[4] += w2 * u4;   // (s_9, s_10)
            f2 u5 = t2 * u4 - u3;   accP[5] += w2 * u5;   // (s_11,s_12)
            f2 u6 = t2 * u5 - u4;   accP[6] += w2 * u6;   // (s_13,s_14)
            float s15 = fmaf(twoc2, u6.x, -u5.x);
            acc15 = fmaf(w, s15, acc15);
        }
    }

    float accv[16];
    accv[0] = acc0;
#pragma unroll
    for (int j = 0; j < 7; ++j) { accv[2 * j + 1] = accP[j].x; accv[2 * j + 2] = accP[j].y; }
    accv[15] = acc15;

    // 16 -> 8 -> 4 -> 2 -> 1 (disjoint stage buffers; write-then-sync-then-read)
    if (wv >= 8) {
#pragma unroll
        for (int k = 0; k < CC; ++k) S1[wv - 8][lane][k] = accv[k];
    }
    __syncthreads();
    if (wv < 8) {
#pragma unroll
        for (int k = 0; k < CC; ++k) accv[k] += S1[wv][lane][k];
    }
    if (wv >= 4 && wv < 8) {
#pragma unroll
        for (int k = 0; k < CC; ++k) S2[wv - 4][lane][k] = accv[k];
    }
    __syncthreads();
    if (wv < 4) {
#pragma unroll
        for (int k = 0; k < CC; ++k) accv[k] += S2[wv][lane][k];
    }
    if (wv == 2 || wv == 3) {
#pragma unroll
        for (int k = 0; k < CC; ++k) S3[wv - 2][lane][k] = accv[k];
    }
    __syncthreads();
    if (wv < 2) {
#pragma unroll
        for (int k = 0; k < CC; ++k) accv[k] += S3[wv][lane][k];
    }
    if (wv == 1) {
#pragma unroll
        for (int k = 0; k < CC; ++k) S4[lane][k] = accv[k];
    }
    __syncthreads();
    if (wv == 0) {
        int xo = tx * 8 + (lane & 7);
        int yo = ty * 8 + (lane >> 3);
#pragma unroll
        for (int k = 0; k < CC; ++k) {
            float val = accv[k] + S4[lane][k];
            float scale = (k == 0) ? 1.f : (-2.f / (PIF * (float)k));
            out[(((b * CC + k) * HH) + yo) * HH + xo] = val * scale;
        }
    }
}

extern "C" void kernel_launch(void* const* d_in, const int* in_sizes, int n_in,
                              void* d_out, int out_size, void* d_ws, size_t ws_size,
                              hipStream_t stream) {
    const float* v = (const float*)d_in[0];
    float* out = (float*)d_out;

    // ws: recf 2048*16*4 = 131072 B | recd 2048*10*8 = 163840 B | bbox 8192 B
    float*  recf = (float*)d_ws;
    double* recd = (double*)((char*)d_ws + 131072);
    int*    bbox = (int*)((char*)d_ws + 131072 + 163840);

    fof_setup<<<(BB * FF + 255) / 256, 256, 0, stream>>>(v, recf, recd, bbox);
    fof_main<<<BB * 256, 1024, 0, stream>>>(recf, recd, bbox, out);
}

// Round 7
// 75.533 us; speedup vs baseline: 1.4970x; 1.0755x over previous
//
#include <hip/hip_runtime.h>
#include <math.h>

#define HH 128
#define BB 2
#define FF 1024
#define CC 16
#define PIF 3.14159265358979323846f

typedef float f2 __attribute__((ext_vector_type(2)));

// ---------------------------------------------------------------------------
// Kernel 1: per-face setup (once, 2048 threads total).
// f32 record (16 floats, 64B -> one s_load_dwordx16):
//   [0..8]  A0 B0 C0 A1 B1 C1 A2 B2 C2   (l_i = A*py + B*px + C, 1/area folded)
//   [9..11] ZA ZB ZC                     (zt = clamp(ZA*py+ZB*px+ZC, 0, 1))
//   [12]    sg   [13] eps (f32 sign-uncertainty band)   [14..15] pad
// f64 record (10 doubles): [0..8] the same A..C in f64, [9] pad. Used only
// when some lane's min|l_f32| < eps: f64 signs reproduce the exact decisions
// (R3/R4/R6 evidence: absmax 0.008-0.016 vs threshold 0.565).
// ---------------------------------------------------------------------------
__global__ __launch_bounds__(256) void fof_setup(const float* __restrict__ v,
                                                 float* __restrict__ recf,
                                                 double* __restrict__ recd,
                                                 int* __restrict__ bbox) {
    int idx = blockIdx.x * 256 + threadIdx.x;
    if (idx >= BB * FF) return;
    const float* vp = v + (size_t)idx * 9;

    double X0 = fma((double)vp[0],  64.0, 63.5);
    double Y0 = fma((double)vp[1], -64.0, 63.5);
    double Z0 = (double)vp[2];
    double X1 = fma((double)vp[3],  64.0, 63.5);
    double Y1 = fma((double)vp[4], -64.0, 63.5);
    double Z1 = (double)vp[5];
    double X2 = fma((double)vp[6],  64.0, 63.5);
    double Y2 = fma((double)vp[7], -64.0, 63.5);
    double Z2 = (double)vp[8];

    double d0x = X2 - X1, d0y = Y2 - Y1;
    double d1x = X0 - X2, d1y = Y0 - Y2;
    double d2x = X1 - X0, d2y = Y1 - Y0;
    double area = d1x * d2y - d1y * d2x;
    double inv  = (area != 0.0) ? 1.0 / area : 0.0;
    double sg   = (area > 0.0) ? 1.0 : ((area < 0.0) ? -1.0 : 0.0);

    double A0 = d0x * inv, B0 = -d0y * inv, C0 = (d0y * X1 - d0x * Y1) * inv;
    double A1 = d1x * inv, B1 = -d1y * inv, C1 = (d1y * X2 - d1x * Y2) * inv;
    double A2 = d2x * inv, B2 = -d2y * inv, C2 = (d2y * X0 - d2x * Y0) * inv;

    double ZA = (A0 * Z0 + A1 * Z1 + A2 * Z2) * 0.5;
    double ZB = (B0 * Z0 + B1 * Z1 + B2 * Z2) * 0.5;
    double ZC = (C0 * Z0 + C1 * Z1 + C2 * Z2 + 1.0) * 0.5;

    // f32 sign-uncertainty band: covers f64->f32 coeff conversion (2^-24 rel)
    // + 2-fma f32 eval rounding, on |py|,|px| <= 127 (135 margin). 3x slack.
    double M0 = (fabs(A0) + fabs(B0)) * 135.0 + fabs(C0);
    double M1 = (fabs(A1) + fabs(B1)) * 135.0 + fabs(C1);
    double M2 = (fabs(A2) + fabs(B2)) * 135.0 + fabs(C2);
    float eps = (float)(1e-6 * fmax(M0, fmax(M1, M2)));

    float* rf = recf + (size_t)idx * 16;
    rf[0] = (float)A0; rf[1] = (float)B0; rf[2] = (float)C0;
    rf[3] = (float)A1; rf[4] = (float)B1; rf[5] = (float)C1;
    rf[6] = (float)A2; rf[7] = (float)B2; rf[8] = (float)C2;
    rf[9] = (float)ZA; rf[10] = (float)ZB; rf[11] = (float)ZC;
    rf[12] = (float)sg; rf[13] = eps; rf[14] = 0.f; rf[15] = 0.f;

    double* rd = recd + (size_t)idx * 10;
    rd[0] = A0; rd[1] = B0; rd[2] = C0;
    rd[3] = A1; rd[4] = B1; rd[5] = C1;
    rd[6] = A2; rd[7] = B2; rd[8] = C2; rd[9] = 0.0;

    float x0 = (float)X0, y0 = (float)Y0;
    float x1 = (float)X1, y1 = (float)Y1;
    float x2 = (float)X2, y2 = (float)Y2;
    float xmn = fminf(x0, fminf(x1, x2)) - 0.5f;
    float xmx = fmaxf(x0, fmaxf(x1, x2)) + 0.5f;
    float ymn = fminf(y0, fminf(y1, y2)) - 0.5f;
    float ymx = fmaxf(y0, fmaxf(y1, y2)) + 0.5f;
    int txmin = (int)ceilf((xmn - 7.f) * 0.125f);
    int txmax = (int)floorf(xmx * 0.125f);
    int tymin = (int)ceilf((ymn - 7.f) * 0.125f);
    int tymax = (int)floorf(ymx * 0.125f);
    txmin = max(0, min(15, txmin)); txmax = max(0, min(15, txmax));
    tymin = max(0, min(15, tymin)); tymax = max(0, min(15, tymax));
    bbox[idx] = (sg == 0.0) ? (1 | (0 << 8) | (1 << 16) | (0 << 24))
                            : (txmin | (txmax << 8) | (tymin << 16) | (tymax << 24));
}

// ---------------------------------------------------------------------------
// Kernel 2: main. 512 blocks x 1024 threads; 16 waves x 64 faces = all 1024
// faces -> block writes FINAL scaled output. Block->(batch,tile) mapping is
// load-balance-aware: b = blk&1, tile = b ? (blk>>1)^0x88 : blk>>1.
//   - depth-first CU fill pairs (2c,2c+1) -> (t, t^0x88): center<->corner.
//   - breadth-first fill pairs (c, c+256) -> (t, t+128): vertical flip.
// Either way a CU's two resident blocks sum to ~avg load (worst ~1.2x avg)
// instead of the previous same-tile-twice 2x-central pathology.
// ---------------------------------------------------------------------------
__global__ __launch_bounds__(1024) void fof_main(const float* __restrict__ recf,
                                                 const double* __restrict__ recd,
                                                 const int* __restrict__ bbox,
                                                 float* __restrict__ out) {
    __shared__ float S1[8][64][17];
    __shared__ float S2[4][64][17];
    __shared__ float S3[2][64][17];
    __shared__ float S4[64][17];

    int blk  = blockIdx.x;                 // 0..511
    int b    = blk & 1;
    int t0   = blk >> 1;                   // 0..255
    int tile = b ? (t0 ^ 0x88) : t0;       // heavy<->light pairing
    int ty   = tile >> 4;
    int tx   = tile & 15;
    int wv   = __builtin_amdgcn_readfirstlane((int)(threadIdx.x >> 6));  // 0..15
    int lane = threadIdx.x & 63;

    float px = (float)(tx * 8 + (lane & 7));
    float py = (float)(ty * 8 + (lane >> 3));

    float acc0 = 0.f, acc15 = 0.f;
    f2 accP[7];
#pragma unroll
    for (int j = 0; j < 7; ++j) { accP[j].x = 0.f; accP[j].y = 0.f; }

    int gfb = b * FF + wv * 64;            // this wave's 64-face chunk

    int pk = bbox[gfb + lane];
    int txmin = pk & 255, txmax = (pk >> 8) & 255;
    int tymin = (pk >> 16) & 255, tymax = (pk >> 24) & 255;
    bool pass = !((tx < txmin) | (tx > txmax) | (ty < tymin) | (ty > tymax));
    unsigned long long m = __ballot(pass);

    while (m) {
        int j = __builtin_ctzll(m);
        m &= m - 1;
        j = __builtin_amdgcn_readfirstlane(j);           // wave-uniform index
        const float* r = recf + (size_t)(gfb + j) * 16;  // -> s_load_dwordx16

        float l0 = fmaf(r[0], py, fmaf(r[1], px, r[2]));
        float l1 = fmaf(r[3], py, fmaf(r[4], px, r[5]));
        float l2 = fmaf(r[6], py, fmaf(r[7], px, r[8]));
        float eps = r[13];
        // v_min3-shaped tests (exact reformulation of all-3 predicates)
        float lmin = fminf(fminf(l0, l1), l2);
        float amin = fminf(fminf(__builtin_fabsf(l0), __builtin_fabsf(l1)),
                           __builtin_fabsf(l2));
        bool inside = lmin >= 0.f;
        bool unc    = amin < eps;
        if (__builtin_expect(__any(unc), 0)) {           // rare exact path
            const double* rd = recd + (size_t)(gfb + j) * 10;
            double pyd = (double)py, pxd = (double)px;
            double L0 = fma(rd[0], pyd, fma(rd[1], pxd, rd[2]));
            double L1 = fma(rd[3], pyd, fma(rd[4], pxd, rd[5]));
            double L2 = fma(rd[6], pyd, fma(rd[7], pxd, rd[8]));
            inside = (L0 >= 0.0) & (L1 >= 0.0) & (L2 >= 0.0);
        }
        float w = inside ? r[12] : 0.f;

        if (__any(w != 0.f)) {
            float zt = fmaf(r[9], py, fmaf(r[10], px, r[11]));
            zt = fminf(fmaxf(zt, 0.f), 1.f);
            // HW trig in revolutions: sin(pi*zt)=vsin(zt/2), sin(2pi*zt)=vsin(zt),
            // cos(2pi*zt)=vcos(zt). Range [0,1] rev -> no argument reduction.
            float hz = 0.5f * zt;
            float s1, s2, c2;
            asm("v_sin_f32 %0, %1" : "=v"(s1) : "v"(hz));
            asm("v_sin_f32 %0, %1" : "=v"(s2) : "v"(zt));
            asm("v_cos_f32 %0, %1" : "=v"(c2) : "v"(zt));
            float twoc2 = c2 + c2;

            acc0 = fmaf(w, 1.f - zt, acc0);
            f2 w2;  w2.x = w;      w2.y = w;
            f2 t2;  t2.x = twoc2;  t2.y = twoc2;
            f2 um1; um1.x = -s1;   um1.y = 0.f;   // (s_{-1}, s_0)
            f2 u0;  u0.x = s1;     u0.y = s2;     // (s_1, s_2)
            accP[0] += w2 * u0;
            f2 u1 = t2 * u0 - um1;  accP[1] += w2 * u1;   // (s_3, s_4)
            f2 u2 = t2 * u1 - u0;   accP[2] += w2 * u2;   // (s_5, s_6)
            f2 u3 = t2 * u2 - u1;   accP[3] += w2 * u3;   // (s_7, s_8)
            f2 u4 = t2 * u3 - u2;   accP[4] += w2 * u4;   // (s_9, s_10)
            f2 u5 = t2 * u4 - u3;   accP[5] += w2 * u5;   // (s_11,s_12)
            f2 u6 = t2 * u5 - u4;   accP[6] += w2 * u6;   // (s_13,s_14)
            float s15 = fmaf(twoc2, u6.x, -u5.x);
            acc15 = fmaf(w, s15, acc15);
        }
    }

    float accv[16];
    accv[0] = acc0;
#pragma unroll
    for (int j = 0; j < 7; ++j) { accv[2 * j + 1] = accP[j].x; accv[2 * j + 2] = accP[j].y; }
    accv[15] = acc15;

    // 16 -> 8 -> 4 -> 2 -> 1 (disjoint stage buffers; write-then-sync-then-read)
    if (wv >= 8) {
#pragma unroll
        for (int k = 0; k < CC; ++k) S1[wv - 8][lane][k] = accv[k];
    }
    __syncthreads();
    if (wv < 8) {
#pragma unroll
        for (int k = 0; k < CC; ++k) accv[k] += S1[wv][lane][k];
    }
    if (wv >= 4 && wv < 8) {
#pragma unroll
        for (int k = 0; k < CC; ++k) S2[wv - 4][lane][k] = accv[k];
    }
    __syncthreads();
    if (wv < 4) {
#pragma unroll
        for (int k = 0; k < CC; ++k) accv[k] += S2[wv][lane][k];
    }
    if (wv == 2 || wv == 3) {
#pragma unroll
        for (int k = 0; k < CC; ++k) S3[wv - 2][lane][k] = accv[k];
    }
    __syncthreads();
    if (wv < 2) {
#pragma unroll
        for (int k = 0; k < CC; ++k) accv[k] += S3[wv][lane][k];
    }
    if (wv == 1) {
#pragma unroll
        for (int k = 0; k < CC; ++k) S4[lane][k] = accv[k];
    }
    __syncthreads();
    if (wv == 0) {
        int xo = tx * 8 + (lane & 7);
        int yo = ty * 8 + (lane >> 3);
#pragma unroll
        for (int k = 0; k < CC; ++k) {
            float val = accv[k] + S4[lane][k];
            float scale = (k == 0) ? 1.f : (-2.f / (PIF * (float)k));
            out[(((b * CC + k) * HH) + yo) * HH + xo] = val * scale;
        }
    }
}

extern "C" void kernel_launch(void* const* d_in, const int* in_sizes, int n_in,
                              void* d_out, int out_size, void* d_ws, size_t ws_size,
                              hipStream_t stream) {
    const float* v = (const float*)d_in[0];
    float* out = (float*)d_out;

    // ws: recf 2048*16*4 = 131072 B | recd 2048*10*8 = 163840 B | bbox 8192 B
    float*  recf = (float*)d_ws;
    double* recd = (double*)((char*)d_ws + 131072);
    int*    bbox = (int*)((char*)d_ws + 131072 + 163840);

    fof_setup<<<(BB * FF + 255) / 256, 256, 0, stream>>>(v, recf, recd, bbox);
    fof_main<<<BB * 256, 1024, 0, stream>>>(recf, recd, bbox, out);
}